// Round 1
// baseline (22123.976 us; speedup 1.0000x reference)
//
#include <hip/hip_runtime.h>
#include <stdint.h>

typedef __bf16 bf16x8 __attribute__((ext_vector_type(8)));
typedef float  f32x4  __attribute__((ext_vector_type(4)));

static __device__ __forceinline__ unsigned short f2bf(float f) {
  unsigned int u = __float_as_uint(f);
  u = u + 0x7fffu + ((u >> 16) & 1u);
  return (unsigned short)(u >> 16);
}
static __device__ __forceinline__ float bf2f(unsigned short h) {
  return __uint_as_float(((unsigned int)h) << 16);
}
static __device__ __forceinline__ float sigm(float x) {
  return 1.f / (1.f + __expf(-x));
}
static __device__ __forceinline__ float tanh_f(float x) {
  float ax = fabsf(x);
  float e = __expf(-2.f * ax);
  float t = (1.f - e) / (1.f + e);
  return copysignf(t, x);
}

// ---------------- weight packing (runs every launch; ws is re-poisoned) ----
// Segments (flat):
//  W4 bf16 [3200 x 832]: k<20 Wih4, 20..23 zero, 24..823 Whh4[k-24], 824.. zero
//  W5 bf16 [512 x 928]:  k<800 Wih5, 800..927 Whh5[k-800]
//  W1 f32  [240 x 192]:  k<128 Wih1, 128..187 Whh1, 188.. zero
//  W2 f32  [80 x 80]:    k<60 Wih21, 60..79 Whh21
//  W3 f32  [80 x 40]:    k<20 Wih3, 20..39 Whh3
//  b4[3200], b5[512], b1[240], b2[80], b3[80] (bih+bhh)
__global__ void kPrep(const float* __restrict__ w4i, const float* __restrict__ w4h,
                      const float* __restrict__ b4i, const float* __restrict__ b4h,
                      const float* __restrict__ w5i, const float* __restrict__ w5h,
                      const float* __restrict__ b5i, const float* __restrict__ b5h,
                      const float* __restrict__ w1i, const float* __restrict__ w1h,
                      const float* __restrict__ b1i, const float* __restrict__ b1h,
                      const float* __restrict__ w2i, const float* __restrict__ w2h,
                      const float* __restrict__ b2i, const float* __restrict__ b2h,
                      const float* __restrict__ w3i, const float* __restrict__ w3h,
                      const float* __restrict__ b3i, const float* __restrict__ b3h,
                      unsigned short* __restrict__ W4, unsigned short* __restrict__ W5,
                      float* __restrict__ W1, float* __restrict__ W2, float* __restrict__ W3,
                      float* __restrict__ b4, float* __restrict__ b5,
                      float* __restrict__ b1, float* __restrict__ b2, float* __restrict__ b3) {
  int idx0 = blockIdx.x * blockDim.x + threadIdx.x;
  int stride = gridDim.x * blockDim.x;
  const int TOT = 3197328;
  for (int i = idx0; i < TOT; i += stride) {
    int i2 = i;
    if (i2 < 2662400) {
      int n = i2 / 832, k = i2 % 832;
      float v = (k < 20) ? w4i[n * 20 + k]
                         : ((k >= 24 && k < 824) ? w4h[n * 800 + (k - 24)] : 0.f);
      W4[i2] = f2bf(v);
      continue;
    }
    i2 -= 2662400;
    if (i2 < 475136) {
      int n = i2 / 928, k = i2 % 928;
      float v = (k < 800) ? w5i[n * 800 + k] : w5h[n * 128 + (k - 800)];
      W5[i2] = f2bf(v);
      continue;
    }
    i2 -= 475136;
    if (i2 < 46080) {
      int n = i2 / 192, k = i2 % 192;
      W1[i2] = (k < 128) ? w1i[n * 128 + k] : ((k < 188) ? w1h[n * 60 + (k - 128)] : 0.f);
      continue;
    }
    i2 -= 46080;
    if (i2 < 6400) {
      int n = i2 / 80, k = i2 % 80;
      W2[i2] = (k < 60) ? w2i[n * 60 + k] : w2h[n * 20 + (k - 60)];
      continue;
    }
    i2 -= 6400;
    if (i2 < 3200) {
      int n = i2 / 40, k = i2 % 40;
      W3[i2] = (k < 20) ? w3i[n * 20 + k] : w3h[n * 20 + (k - 20)];
      continue;
    }
    i2 -= 3200;
    if (i2 < 3200) { b4[i2] = b4i[i2] + b4h[i2]; continue; }
    i2 -= 3200;
    if (i2 < 512) { b5[i2] = b5i[i2] + b5h[i2]; continue; }
    i2 -= 512;
    if (i2 < 240) { b1[i2] = b1i[i2] + b1h[i2]; continue; }
    i2 -= 240;
    if (i2 < 80) { b2[i2] = b2i[i2] + b2h[i2]; continue; }
    i2 -= 80;
    b3[i2] = b3i[i2] + b3h[i2];
  }
}

__global__ void kZero(float* __restrict__ c2, float* __restrict__ c3,
                      unsigned int* __restrict__ h2, unsigned int* __restrict__ h3) {
  int idx = blockIdx.x * blockDim.x + threadIdx.x;
  int stride = gridDim.x * blockDim.x;
  for (int i = idx; i < 819200; i += stride) c2[i] = 0.f;
  for (int i = idx; i < 131072; i += stride) c3[i] = 0.f;
  for (int i = idx; i < 409600; i += stride) h2[i] = 0u;
  for (int i = idx; i < 65536; i += stride) h3[i] = 0u;
}

// ---------------- encoder: fc1 + fc21 fused, 4 batch rows / block ----------
__global__ __launch_bounds__(256, 2)
void kEnc(const float* __restrict__ x,
          const float* __restrict__ W1, const float* __restrict__ b1,
          const float* __restrict__ W2, const float* __restrict__ b2,
          const float* __restrict__ idW, const float* __restrict__ idb,
          float* __restrict__ hl30, float* __restrict__ cl30,
          float* __restrict__ out0, float* __restrict__ muOut) {
  __shared__ float xb[512];
  __shared__ float hb[240], cbb[240], h1b[240];
  __shared__ float h21[80], c21[80];
  __shared__ float g1[960], g2[320];
  const int tid = threadIdx.x;
  const int rowbase = blockIdx.x * 4;
  if (tid < 240) { hb[tid] = 0.f; cbb[tid] = 0.f; h1b[tid] = 0.f; }
  if (tid < 80) { h21[tid] = 0.f; c21[tid] = 0.f; }
  __syncthreads();
  for (int t = 0; t < 256; ++t) {
    const float* xs = x + ((size_t)t * 1024 + rowbase) * 128;
    xb[tid] = xs[tid];
    xb[tid + 256] = xs[tid + 256];
    __syncthreads();
    if (tid < 240) {  // fc1 gates: col tid, 4 rows, K = [x(128) | h(60)]
      const float* wr = W1 + tid * 192;
      float s0 = b1[tid], s1 = s0, s2 = s0, s3 = s0;
      for (int k = 0; k < 128; ++k) {
        float w = wr[k];
        s0 += w * xb[k]; s1 += w * xb[128 + k]; s2 += w * xb[256 + k]; s3 += w * xb[384 + k];
      }
      for (int k = 0; k < 60; ++k) {
        float w = wr[128 + k];
        s0 += w * hb[k]; s1 += w * hb[60 + k]; s2 += w * hb[120 + k]; s3 += w * hb[180 + k];
      }
      g1[tid] = s0; g1[240 + tid] = s1; g1[480 + tid] = s2; g1[720 + tid] = s3;
    }
    __syncthreads();
    if (tid < 240) {  // fc1 cell
      int b = tid / 60, j = tid % 60;
      const float* g = g1 + b * 240;
      float iv = sigm(g[j]), fv = sigm(g[60 + j]), gv = tanh_f(g[120 + j]), ov = sigm(g[180 + j]);
      float c = fv * cbb[b * 60 + j] + iv * gv;
      cbb[b * 60 + j] = c;
      float h = ov * tanh_f(c);
      hb[b * 60 + j] = h;
      h1b[b * 60 + j] = fmaxf(h, 0.f);
    }
    __syncthreads();
    if (tid < 80) {  // fc21 gates: K = [h1(60) | h21(20)]
      const float* wr = W2 + tid * 80;
      float s0 = b2[tid], s1 = s0, s2 = s0, s3 = s0;
      for (int k = 0; k < 60; ++k) {
        float w = wr[k];
        s0 += w * h1b[k]; s1 += w * h1b[60 + k]; s2 += w * h1b[120 + k]; s3 += w * h1b[180 + k];
      }
      for (int k = 0; k < 20; ++k) {
        float w = wr[60 + k];
        s0 += w * h21[k]; s1 += w * h21[20 + k]; s2 += w * h21[40 + k]; s3 += w * h21[60 + k];
      }
      g2[tid] = s0; g2[80 + tid] = s1; g2[160 + tid] = s2; g2[240 + tid] = s3;
    }
    __syncthreads();
    if (tid < 80) {  // fc21 cell
      int b = tid / 20, j = tid % 20;
      const float* g = g2 + b * 80;
      float iv = sigm(g[j]), fv = sigm(g[20 + j]), gv = tanh_f(g[40 + j]), ov = sigm(g[60 + j]);
      float c = fv * c21[b * 20 + j] + iv * gv;
      c21[b * 20 + j] = c;
      h21[b * 20 + j] = ov * tanh_f(c);
    }
    __syncthreads();
  }
  if (tid < 80) {  // mu, c_mean, output0 = mu @ idW^T + idb
    int b = tid / 20, j = tid % 20;
    int gb = rowbase + b;
    float mu = h21[b * 20 + j];
    muOut[(size_t)gb * 20 + j] = mu;
    hl30[gb * 20 + j] = mu;
    cl30[gb * 20 + j] = c21[b * 20 + j];
    float s = idb[j];
    for (int k = 0; k < 20; ++k) s += h21[b * 20 + k] * idW[j * 20 + k];
    out0[gb * 20 + j] = s;
  }
}

// ---------------- decoder kernel 1: down + l3 (scalar) + l4 (MFMA) --------
// grid (13 col-tiles of 64 h2-cols, 32 row-tiles of 32 rows), 256 threads
__global__ __launch_bounds__(256, 2)
void kD1(int t,
         const unsigned short* __restrict__ W4, const float* __restrict__ b4,
         const float* __restrict__ W3, const float* __restrict__ b3,
         const float* __restrict__ dW, const float* __restrict__ db,
         const float* __restrict__ out0,
         const float* __restrict__ hl3_in, const float* __restrict__ cl3_in,
         float* __restrict__ hl3_out, float* __restrict__ cl3_out,
         const unsigned short* __restrict__ h2_in, unsigned short* __restrict__ h2_out,
         float* __restrict__ c2, const unsigned short* __restrict__ h3_in) {
  __shared__ __align__(16) unsigned short lsA[32 * 840];  // 53.76 KB, A = [h|0|h2|0]
  __shared__ float lsHnew[640];
  float* lsOut = (float*)lsA;                    // 640 f32  (bytes 0..2560)
  float* lsGates = (float*)(lsA + 1280);         // 2560 f32 (bytes 2560..12800)
  unsigned short* lsH3p = lsA + 6400;            // 4096 u16 (bytes 12800..20992)

  const int tid = threadIdx.x;
  const int rowbase = blockIdx.y * 32;
  const int cb = blockIdx.x * 64;
  const int ncols = (cb + 64 <= 800) ? 64 : (800 - cb);

  if (t > 0) {  // stage h3_prev tile (32x128 bf16, contiguous)
    const uint4* src = (const uint4*)(h3_in + (size_t)rowbase * 128);
    uint4* dst = (uint4*)lsH3p;
    for (int i = tid; i < 512; i += 256) dst[i] = src[i];
  }
  __syncthreads();
  if (t == 0) {
    for (int i = tid; i < 640; i += 256) {
      int b = i / 20, k = i % 20;
      lsOut[i] = out0[(size_t)(rowbase + b) * 20 + k];
    }
  } else {  // out = h3_prev @ dW^T + db
    for (int i = tid; i < 640; i += 256) {
      int b = i / 20, k = i % 20;
      const float* wr = dW + k * 128;
      const unsigned short* hr = lsH3p + b * 128;
      float s = db[k];
      for (int j = 0; j < 128; ++j) s += bf2f(hr[j]) * wr[j];
      lsOut[i] = s;
    }
  }
  __syncthreads();
  for (int i = tid; i < 2560; i += 256) {  // l3 gates, K = [out(20)|hl3(20)]
    int b = i / 80, n = i % 80;
    const float* wr = W3 + n * 40;
    const float* ob = lsOut + b * 20;
    const float* hp = hl3_in + (size_t)(rowbase + b) * 20;
    float s = b3[n];
    for (int k = 0; k < 20; ++k) s += ob[k] * wr[k];
    for (int k = 0; k < 20; ++k) s += hp[k] * wr[20 + k];
    lsGates[i] = s;
  }
  __syncthreads();
  for (int i = tid; i < 640; i += 256) {  // l3 cell
    int b = i / 20, j = i % 20;
    const float* g = lsGates + b * 80;
    float iv = sigm(g[j]), fv = sigm(g[20 + j]), gv = tanh_f(g[40 + j]), ov = sigm(g[60 + j]);
    float c = fv * cl3_in[(size_t)(rowbase + b) * 20 + j] + iv * gv;
    float h = ov * tanh_f(c);
    lsHnew[i] = h;
    if (blockIdx.x == 0) {
      hl3_out[(size_t)(rowbase + b) * 20 + j] = h;
      cl3_out[(size_t)(rowbase + b) * 20 + j] = c;
    }
  }
  __syncthreads();
  // stage A: cols 0..19 = h_new (bf16), 20..23 = 0, 24..823 = h2_prev, 824..839 = 0
  for (int i = tid; i < 3200; i += 256) {
    int b = i / 100, s = i % 100;
    *(uint4*)(lsA + b * 840 + 24 + s * 8) =
        *(const uint4*)(h2_in + (size_t)(rowbase + b) * 800 + s * 8);
  }
  for (int i = tid; i < 640; i += 256) {
    int b = i / 20, j = i % 20;
    lsA[b * 840 + j] = f2bf(lsHnew[i]);
  }
  for (int i = tid; i < 640; i += 256) {
    int b = i / 20, z = i % 20;
    int col = (z < 4) ? (20 + z) : (820 + z);
    lsA[b * 840 + col] = 0;
  }
  __syncthreads();

  const int w = tid >> 6, lane = tid & 63, quad = lane >> 4, l16 = lane & 15;
  const int jwl = w * 16;
  if (jwl < ncols) {
    const int jw = cb + jwl;
    f32x4 acc[2][4];
#pragma unroll
    for (int mt = 0; mt < 2; ++mt)
#pragma unroll
      for (int g = 0; g < 4; ++g) acc[mt][g] = (f32x4){0.f, 0.f, 0.f, 0.f};
    const unsigned short* Wp = W4 + (size_t)(jw + l16) * 832 + quad * 8;
    const unsigned short* A0 = lsA + l16 * 840 + quad * 8;
    const unsigned short* A1 = lsA + (16 + l16) * 840 + quad * 8;
    for (int kc = 0; kc < 26; ++kc) {
      const int ko = kc * 32;
      bf16x8 a0 = *(const bf16x8*)(A0 + ko);
      bf16x8 a1 = *(const bf16x8*)(A1 + ko);
      bf16x8 bv0 = *(const bf16x8*)(Wp + (size_t)0 * 665600 + ko);
      bf16x8 bv1 = *(const bf16x8*)(Wp + (size_t)1 * 665600 + ko);
      bf16x8 bv2 = *(const bf16x8*)(Wp + (size_t)2 * 665600 + ko);
      bf16x8 bv3 = *(const bf16x8*)(Wp + (size_t)3 * 665600 + ko);
      acc[0][0] = __builtin_amdgcn_mfma_f32_16x16x32_bf16(a0, bv0, acc[0][0], 0, 0, 0);
      acc[1][0] = __builtin_amdgcn_mfma_f32_16x16x32_bf16(a1, bv0, acc[1][0], 0, 0, 0);
      acc[0][1] = __builtin_amdgcn_mfma_f32_16x16x32_bf16(a0, bv1, acc[0][1], 0, 0, 0);
      acc[1][1] = __builtin_amdgcn_mfma_f32_16x16x32_bf16(a1, bv1, acc[1][1], 0, 0, 0);
      acc[0][2] = __builtin_amdgcn_mfma_f32_16x16x32_bf16(a0, bv2, acc[0][2], 0, 0, 0);
      acc[1][2] = __builtin_amdgcn_mfma_f32_16x16x32_bf16(a1, bv2, acc[1][2], 0, 0, 0);
      acc[0][3] = __builtin_amdgcn_mfma_f32_16x16x32_bf16(a0, bv3, acc[0][3], 0, 0, 0);
      acc[1][3] = __builtin_amdgcn_mfma_f32_16x16x32_bf16(a1, bv3, acc[1][3], 0, 0, 0);
    }
    const int j = jw + l16;
    const float bi = b4[j], bff = b4[800 + j], bgg = b4[1600 + j], bo = b4[2400 + j];
#pragma unroll
    for (int mt = 0; mt < 2; ++mt) {
#pragma unroll
      for (int r = 0; r < 4; ++r) {
        int bg = rowbase + mt * 16 + quad * 4 + r;
        float iv = sigm(acc[mt][0][r] + bi);
        float fv = sigm(acc[mt][1][r] + bff);
        float gv = tanh_f(acc[mt][2][r] + bgg);
        float ov = sigm(acc[mt][3][r] + bo);
        size_t ix = (size_t)bg * 800 + j;
        float c = fv * c2[ix] + iv * gv;
        c2[ix] = c;
        h2_out[ix] = f2bf(ov * tanh_f(c));
      }
    }
  }
}

// ---------------- decoder kernel 2: l5 (MFMA) + output write ---------------
// grid (4 col-tiles of 32 h3-cols, 32 row-tiles of 32 rows), 256 threads
__global__ __launch_bounds__(256, 2)
void kD2(int t,
         const unsigned short* __restrict__ W5, const float* __restrict__ b5,
         const unsigned short* __restrict__ h2_cur,
         const unsigned short* __restrict__ h3_in, unsigned short* __restrict__ h3_out,
         float* __restrict__ c3, float* __restrict__ dout) {
  __shared__ __align__(16) unsigned short lsA[32 * 968];  // 61.95 KB, A = [h2|h3prev|0]
  const int tid = threadIdx.x;
  const int rowbase = blockIdx.y * 32;
  const int colbase = blockIdx.x * 32;
  for (int i = tid; i < 3200; i += 256) {
    int b = i / 100, s = i % 100;
    *(uint4*)(lsA + b * 968 + s * 8) =
        *(const uint4*)(h2_cur + (size_t)(rowbase + b) * 800 + s * 8);
  }
  for (int i = tid; i < 512; i += 256) {
    int b = i / 16, s = i % 16;
    *(uint4*)(lsA + b * 968 + 800 + s * 8) =
        *(const uint4*)(h3_in + (size_t)(rowbase + b) * 128 + s * 8);
  }
  for (int i = tid; i < 1280; i += 256) {
    int b = i / 40, z = i % 40;
    lsA[b * 968 + 928 + z] = 0;
  }
  __syncthreads();
  const int w = tid >> 6, lane = tid & 63, quad = lane >> 4, l16 = lane & 15;
  const int mh = w >> 1, jh = w & 1;
  const int j = colbase + jh * 16 + l16;
  f32x4 acc[4];
#pragma unroll
  for (int g = 0; g < 4; ++g) acc[g] = (f32x4){0.f, 0.f, 0.f, 0.f};
  const unsigned short* Wp = W5 + (size_t)j * 928 + quad * 8;
  const unsigned short* Ap = lsA + (mh * 16 + l16) * 968 + quad * 8;
  for (int kc = 0; kc < 29; ++kc) {
    const int ko = kc * 32;
    bf16x8 a = *(const bf16x8*)(Ap + ko);
    bf16x8 bv0 = *(const bf16x8*)(Wp + (size_t)0 * 118784 + ko);
    bf16x8 bv1 = *(const bf16x8*)(Wp + (size_t)1 * 118784 + ko);
    bf16x8 bv2 = *(const bf16x8*)(Wp + (size_t)2 * 118784 + ko);
    bf16x8 bv3 = *(const bf16x8*)(Wp + (size_t)3 * 118784 + ko);
    acc[0] = __builtin_amdgcn_mfma_f32_16x16x32_bf16(a, bv0, acc[0], 0, 0, 0);
    acc[1] = __builtin_amdgcn_mfma_f32_16x16x32_bf16(a, bv1, acc[1], 0, 0, 0);
    acc[2] = __builtin_amdgcn_mfma_f32_16x16x32_bf16(a, bv2, acc[2], 0, 0, 0);
    acc[3] = __builtin_amdgcn_mfma_f32_16x16x32_bf16(a, bv3, acc[3], 0, 0, 0);
  }
  const float bi = b5[j], bff = b5[128 + j], bgg = b5[256 + j], bo = b5[384 + j];
#pragma unroll
  for (int r = 0; r < 4; ++r) {
    int bg = rowbase + mh * 16 + quad * 4 + r;
    float iv = sigm(acc[0][r] + bi);
    float fv = sigm(acc[1][r] + bff);
    float gv = tanh_f(acc[2][r] + bgg);
    float ov = sigm(acc[3][r] + bo);
    size_t ix = (size_t)bg * 128 + j;
    float c = fv * c3[ix] + iv * gv;
    c3[ix] = c;
    float h = ov * tanh_f(c);
    dout[(size_t)t * 131072 + ix] = h;   // outMean[t] = h3
    h3_out[ix] = f2bf(h);
  }
}

extern "C" void kernel_launch(void* const* d_in, const int* in_sizes, int n_in,
                              void* d_out, int out_size, void* d_ws, size_t ws_size,
                              hipStream_t stream) {
  (void)in_sizes; (void)n_in; (void)out_size; (void)ws_size;
  const float* x   = (const float*)d_in[0];
  const float* w1i = (const float*)d_in[1];
  const float* w1h = (const float*)d_in[2];
  const float* b1i = (const float*)d_in[3];
  const float* b1h = (const float*)d_in[4];
  const float* w2i = (const float*)d_in[5];
  const float* w2h = (const float*)d_in[6];
  const float* b2i = (const float*)d_in[7];
  const float* b2h = (const float*)d_in[8];
  const float* w3i = (const float*)d_in[9];
  const float* w3h = (const float*)d_in[10];
  const float* b3i = (const float*)d_in[11];
  const float* b3h = (const float*)d_in[12];
  const float* w4i = (const float*)d_in[13];
  const float* w4h = (const float*)d_in[14];
  const float* b4i = (const float*)d_in[15];
  const float* b4h = (const float*)d_in[16];
  const float* w5i = (const float*)d_in[17];
  const float* w5h = (const float*)d_in[18];
  const float* b5i = (const float*)d_in[19];
  const float* b5h = (const float*)d_in[20];
  const float* idW = (const float*)d_in[21];
  const float* idb = (const float*)d_in[22];
  const float* dW  = (const float*)d_in[23];
  const float* db  = (const float*)d_in[24];
  float* out = (float*)d_out;

  char* ws = (char*)d_ws;
  size_t off = 0;
  auto alloc = [&](size_t bytes) -> void* {
    void* p = ws + off;
    off = (off + bytes + 255) & ~(size_t)255;
    return p;
  };
  unsigned short* W4 = (unsigned short*)alloc(3200 * 832 * 2);
  unsigned short* W5 = (unsigned short*)alloc(512 * 928 * 2);
  float* W1 = (float*)alloc(240 * 192 * 4);
  float* W2 = (float*)alloc(80 * 80 * 4);
  float* W3 = (float*)alloc(80 * 40 * 4);
  float* b4 = (float*)alloc(3200 * 4);
  float* b5 = (float*)alloc(512 * 4);
  float* b1 = (float*)alloc(240 * 4);
  float* b2 = (float*)alloc(80 * 4);
  float* b3 = (float*)alloc(80 * 4);
  unsigned short* h2buf = (unsigned short*)alloc(2 * 1024 * 800 * 2);
  unsigned short* h3buf = (unsigned short*)alloc(2 * 1024 * 128 * 2);
  float* c2 = (float*)alloc(1024 * 800 * 4);
  float* c3 = (float*)alloc(1024 * 128 * 4);
  float* hl3 = (float*)alloc(2 * 1024 * 20 * 4);
  float* cl3 = (float*)alloc(2 * 1024 * 20 * 4);
  float* out0 = (float*)alloc(1024 * 20 * 4);

  kPrep<<<dim3(4096), dim3(256), 0, stream>>>(
      w4i, w4h, b4i, b4h, w5i, w5h, b5i, b5h, w1i, w1h, b1i, b1h,
      w2i, w2h, b2i, b2h, w3i, w3h, b3i, b3h,
      W4, W5, W1, W2, W3, b4, b5, b1, b2, b3);
  kZero<<<dim3(2048), dim3(256), 0, stream>>>(c2, c3, (unsigned int*)h2buf,
                                              (unsigned int*)h3buf);
  kEnc<<<dim3(256), dim3(256), 0, stream>>>(x, W1, b1, W2, b2, idW, idb,
                                            hl3, cl3, out0, out + 33554432);

  for (int t = 0; t < 256; ++t) {
    int p = t & 1;
    const unsigned short* h2_in = h2buf + (size_t)p * 819200;
    unsigned short* h2_out = h2buf + (size_t)(1 - p) * 819200;
    const unsigned short* h3_in = h3buf + (size_t)p * 131072;
    unsigned short* h3_out = h3buf + (size_t)(1 - p) * 131072;
    const float* hl3_in = hl3 + (size_t)p * 20480;
    float* hl3_out = hl3 + (size_t)(1 - p) * 20480;
    const float* cl3_in = cl3 + (size_t)p * 20480;
    float* cl3_out = cl3 + (size_t)(1 - p) * 20480;
    kD1<<<dim3(13, 32), dim3(256), 0, stream>>>(
        t, W4, b4, W3, b3, dW, db, out0, hl3_in, cl3_in, hl3_out, cl3_out,
        h2_in, h2_out, c2, h3_in);
    kD2<<<dim3(4, 32), dim3(256), 0, stream>>>(t, W5, b5, h2_out, h3_in, h3_out,
                                               c3, out);
  }
}